// Round 13
// baseline (15.620 us; speedup 1.0000x reference)
//
#include <hip/hip_runtime.h>
#include <math.h>

#define BLOCK 256
#define TPT 2   // tokens per thread

typedef float v4f __attribute__((ext_vector_type(4)));

// Even/odd-parity partial sums monoid for type-2 roots. E and O are sums of
// POSITIVE partial weight-products of actual parity classes — every
// intermediate is bounded by the softmax denominator (numerically safe).
// (The Π(g±h) product shortcut is NOT safe — R8's absmax=1.02 failure.)
struct EO { float E, O; };
__device__ __forceinline__ EO mergeEO(EO a, EO b) {
    EO r;
    r.E = fmaf(a.E, b.E, a.O * b.O);
    r.O = fmaf(a.E, b.O, a.O * b.E);
    return r;
}

// weights = softmax(20 * x.r) over 240 unit-norm E8 roots, closed form (O(8)):
//  Type-1 (112): rank-1 factorization A=u+v, B=u-v, u=s*g^2, v=s*h^2
//  Type-2 (128): even-parity monoid over (g,h)
//  g/h = exp2(+-K2*x_j - C/8), s = exp2(-C/4), C = (20/ln2)*|x| (all exps <= 0).
// NOTE: materialized pre[]/suf[]/ex[] arrays on purpose (R6/R12 version): the
// pre- and suf-chains run in parallel and the 6 ex-merges are independent —
// better per-thread ILP than the fused running-prefix walk (R9/R11, ~1us slower).
__device__ __forceinline__ void e8q_token(const float xs[8], float o[8]) {
    float n2 = 0.0f;
#pragma unroll
    for (int j = 0; j < 8; ++j) n2 = fmaf(xs[j], xs[j], n2);
    const float xn = __builtin_amdgcn_sqrtf(n2);

    const float K2 = 10.201358186637847f;       // (20/ln2)/(2*sqrt(2))
    const float C  = 28.853900817779268f * xn;  // (20/ln2)*|x|
    const float Ce = 0.125f * C;
    const float s  = __builtin_amdgcn_exp2f(-0.25f * C);

    float A[8], B[8], g[8], h[8];
#pragma unroll
    for (int j = 0; j < 8; ++j) {
        g[j] = __builtin_amdgcn_exp2f(fmaf(K2, xs[j], -Ce));
        h[j] = __builtin_amdgcn_exp2f(fmaf(-K2, xs[j], -Ce));
        float a = g[j] * g[j];
        float b = h[j] * h[j];
        float sa = s * a;                // u_j
        A[j] = fmaf(s, b, sa);           // u + v
        B[j] = fmaf(-s, b, sa);          // u - v
    }

    // Type-1: exclude-one sums via prefix+suffix adds (no cancelling subtraction)
    float preA[8], sufA[8];
    preA[0] = A[0];
#pragma unroll
    for (int j = 1; j < 8; ++j) preA[j] = preA[j - 1] + A[j];
    sufA[7] = A[7];
#pragma unroll
    for (int j = 6; j >= 0; --j) sufA[j] = sufA[j + 1] + A[j];

    float EA[8];
    EA[0] = sufA[1];
    EA[7] = preA[6];
#pragma unroll
    for (int j = 1; j < 7; ++j) EA[j] = preA[j - 1] + sufA[j + 1];

    float s1 = 0.0f;   // sum_{i<j} A_i A_j (all 112 type-1 weights)
#pragma unroll
    for (int j = 0; j < 7; ++j) s1 = fmaf(A[j], sufA[j + 1], s1);

    // Type-2: parity monoid prefix/suffix (two parallel chains, independent merges)
    EO pre[8], suf[8];
    pre[0] = {g[0], h[0]};
#pragma unroll
    for (int j = 1; j < 8; ++j) pre[j] = mergeEO(pre[j - 1], {g[j], h[j]});
    suf[7] = {g[7], h[7]};
#pragma unroll
    for (int j = 6; j >= 1; --j) suf[j] = mergeEO({g[j], h[j]}, suf[j + 1]);

    const float s2 = pre[7].E;

    EO ex[8];
    ex[0] = suf[1];
    ex[7] = pre[6];
#pragma unroll
    for (int j = 1; j < 7; ++j) ex[j] = mergeEO(pre[j - 1], suf[j + 1]);

    const float inv = __builtin_amdgcn_rcpf(s1 + s2);
    const float c1 = 0.70710678118654752f * inv;   // 1/sqrt2
    const float c2 = 0.35355339059327376f * inv;   // 1/(2*sqrt2)

#pragma unroll
    for (int j = 0; j < 8; ++j) {
        float t1 = B[j] * EA[j];
        float t2 = fmaf(g[j], ex[j].E, -(h[j] * ex[j].O));
        o[j] = fmaf(c1, t1, c2 * t2);
    }
}

// R12's structure, with ONE change: plain (cached) stores instead of
// nontemporal. x and out both fit in the 256MB Infinity Cache; streaming
// writes to HBM paid 33.5MB of HBM BW per replay for data that a writeback
// cache would simply re-dirty in place. Single-variable A/B vs R12.
__global__ __launch_bounds__(BLOCK, 4) void e8q_kernel(const float* __restrict__ x,
                                                       float* __restrict__ out) {
    __shared__ v4f outA[4][64 * TPT];
    __shared__ v4f outB[4][64 * TPT];

    const int tid = threadIdx.x;
    const int w = tid >> 6;      // wave id
    const int l = tid & 63;      // lane id
    const size_t T0 = (size_t)blockIdx.x * (BLOCK * TPT);

    // Issue all loads up front (4x dwordx4) for MLP.
    v4f xv[TPT][2];
#pragma unroll
    for (int p = 0; p < TPT; ++p) {
        const v4f* xp = (const v4f*)(x + (T0 + tid + (size_t)p * BLOCK) * 8);
        xv[p][0] = xp[0];
        xv[p][1] = xp[1];
    }

    // Compute + stage. Pass p, lane l -> block-token p*256 + 64w + l,
    // wave-local token index tl = 64p + l.
#pragma unroll
    for (int p = 0; p < TPT; ++p) {
        float xs[8] = {xv[p][0].x, xv[p][0].y, xv[p][0].z, xv[p][0].w,
                       xv[p][1].x, xv[p][1].y, xv[p][1].z, xv[p][1].w};
        float o[8];
        e8q_token(xs, o);
        const int tl = p * 64 + l;
        outA[w][tl] = (v4f){o[0], o[1], o[2], o[3]};
        outB[w][tl] = (v4f){o[4], o[5], o[6], o[7]};
    }

    // Dense flush, wave-local (no barrier). Wave w's tokens occupy v4f-slot
    // ranges [128w, 128w+128) and [512+128w, 512+128w+128) within the block.
    v4f* ov = (v4f*)out + T0 * 2;
#pragma unroll
    for (int j = 0; j < 2 * TPT; ++j) {
        const int s = j * 64 + l;                       // wave-local slot 0..255
        v4f val = (s & 1) ? outB[w][s >> 1] : outA[w][s >> 1];
        const int gslot = (j < 2) ? (128 * w + j * 64 + l)
                                  : (512 + 128 * w + (j - 2) * 64 + l);
        ov[gslot] = val;
    }
}

extern "C" void kernel_launch(void* const* d_in, const int* in_sizes, int n_in,
                              void* d_out, int out_size, void* d_ws, size_t ws_size,
                              hipStream_t stream) {
    const float* x = (const float*)d_in[0];
    float* out = (float*)d_out;

    const int tokens = in_sizes[0] / 8;        // 1,048,576
    const int grid = tokens / (BLOCK * TPT);   // 2048

    e8q_kernel<<<grid, BLOCK, 0, stream>>>(x, out);
}

// Round 14
// 13.656 us; speedup vs baseline: 1.1438x; 1.1438x over previous
//
#include <hip/hip_runtime.h>
#include <math.h>

#define BLOCK 256
#define TPT 2   // tokens per thread

typedef float v4f __attribute__((ext_vector_type(4)));

// Even/odd-parity partial sums monoid for type-2 roots. E and O are sums of
// POSITIVE partial weight-products of actual parity classes — every
// intermediate is bounded by the softmax denominator (numerically safe).
// (The Π(g±h) product shortcut is NOT safe — R8's absmax=1.02 failure.)
struct EO { float E, O; };
__device__ __forceinline__ EO mergeEO(EO a, EO b) {
    EO r;
    r.E = fmaf(a.E, b.E, a.O * b.O);
    r.O = fmaf(a.E, b.O, a.O * b.E);
    return r;
}

// weights = softmax(20 * x.r) over 240 unit-norm E8 roots, closed form (O(8)):
//  Type-1 (112): rank-1 factorization A=u+v, B=u-v, u=s*g^2, v=s*h^2
//  Type-2 (128): even-parity monoid over (g,h)
//  g/h = exp2(+-K2*x_j - C/8), s = exp2(-C/4), C = (20/ln2)*|x| (all exps <= 0).
// Materialized pre[]/suf[]/ex[] arrays on purpose (R6/R12 version): the
// pre- and suf-chains run in parallel and the 6 ex-merges are independent —
// better per-thread ILP than the fused running-prefix walk (R9/R11, ~1us slower).
__device__ __forceinline__ void e8q_token(const float xs[8], float o[8]) {
    float n2 = 0.0f;
#pragma unroll
    for (int j = 0; j < 8; ++j) n2 = fmaf(xs[j], xs[j], n2);
    const float xn = __builtin_amdgcn_sqrtf(n2);

    const float K2 = 10.201358186637847f;       // (20/ln2)/(2*sqrt(2))
    const float C  = 28.853900817779268f * xn;  // (20/ln2)*|x|
    const float Ce = 0.125f * C;
    const float s  = __builtin_amdgcn_exp2f(-0.25f * C);

    float A[8], B[8], g[8], h[8];
#pragma unroll
    for (int j = 0; j < 8; ++j) {
        g[j] = __builtin_amdgcn_exp2f(fmaf(K2, xs[j], -Ce));
        h[j] = __builtin_amdgcn_exp2f(fmaf(-K2, xs[j], -Ce));
        float a = g[j] * g[j];
        float b = h[j] * h[j];
        float sa = s * a;                // u_j
        A[j] = fmaf(s, b, sa);           // u + v
        B[j] = fmaf(-s, b, sa);          // u - v
    }

    // Type-1: exclude-one sums via prefix+suffix adds (no cancelling subtraction)
    float preA[8], sufA[8];
    preA[0] = A[0];
#pragma unroll
    for (int j = 1; j < 8; ++j) preA[j] = preA[j - 1] + A[j];
    sufA[7] = A[7];
#pragma unroll
    for (int j = 6; j >= 0; --j) sufA[j] = sufA[j + 1] + A[j];

    float EA[8];
    EA[0] = sufA[1];
    EA[7] = preA[6];
#pragma unroll
    for (int j = 1; j < 7; ++j) EA[j] = preA[j - 1] + sufA[j + 1];

    float s1 = 0.0f;   // sum_{i<j} A_i A_j (all 112 type-1 weights)
#pragma unroll
    for (int j = 0; j < 7; ++j) s1 = fmaf(A[j], sufA[j + 1], s1);

    // Type-2: parity monoid prefix/suffix (two parallel chains, independent merges)
    EO pre[8], suf[8];
    pre[0] = {g[0], h[0]};
#pragma unroll
    for (int j = 1; j < 8; ++j) pre[j] = mergeEO(pre[j - 1], {g[j], h[j]});
    suf[7] = {g[7], h[7]};
#pragma unroll
    for (int j = 6; j >= 1; --j) suf[j] = mergeEO({g[j], h[j]}, suf[j + 1]);

    const float s2 = pre[7].E;

    EO ex[8];
    ex[0] = suf[1];
    ex[7] = pre[6];
#pragma unroll
    for (int j = 1; j < 7; ++j) ex[j] = mergeEO(pre[j - 1], suf[j + 1]);

    const float inv = __builtin_amdgcn_rcpf(s1 + s2);
    const float c1 = 0.70710678118654752f * inv;   // 1/sqrt2
    const float c2 = 0.35355339059327376f * inv;   // 1/(2*sqrt2)

#pragma unroll
    for (int j = 0; j < 8; ++j) {
        float t1 = B[j] * EA[j];
        float t2 = fmaf(g[j], ex[j].E, -(h[j] * ex[j].O));
        o[j] = fmaf(c1, t1, c2 * t2);
    }
}

// R12's structure (nontemporal stores CONFIRMED by R13's A/B: plain cached
// stores cost +1.9us) with per-pass interleaved flush: pass p's wave-local
// slots are exactly [128p, 128p+128), so its 2 dense nt stores can issue
// right after its staging — overlapping pass p+1's compute and starting the
// HBM write stream mid-kernel instead of bunching it at the tail.
__global__ __launch_bounds__(BLOCK, 4) void e8q_kernel(const float* __restrict__ x,
                                                       float* __restrict__ out) {
    __shared__ v4f outA[4][64 * TPT];
    __shared__ v4f outB[4][64 * TPT];

    const int tid = threadIdx.x;
    const int w = tid >> 6;      // wave id
    const int l = tid & 63;      // lane id
    const size_t T0 = (size_t)blockIdx.x * (BLOCK * TPT);
    v4f* ov = (v4f*)out + T0 * 2;

    // Issue all loads up front (4x dwordx4) for MLP.
    v4f xv[TPT][2];
#pragma unroll
    for (int p = 0; p < TPT; ++p) {
        const v4f* xp = (const v4f*)(x + (T0 + tid + (size_t)p * BLOCK) * 8);
        xv[p][0] = xp[0];
        xv[p][1] = xp[1];
    }

#pragma unroll
    for (int p = 0; p < TPT; ++p) {
        // Compute pass p (block-token p*256 + 64w + l).
        float xs[8] = {xv[p][0].x, xv[p][0].y, xv[p][0].z, xv[p][0].w,
                       xv[p][1].x, xv[p][1].y, xv[p][1].z, xv[p][1].w};
        float o[8];
        e8q_token(xs, o);

        // Stage to wave-local parity-split LDS.
        const int tl = p * 64 + l;
        outA[w][tl] = (v4f){o[0], o[1], o[2], o[3]};
        outB[w][tl] = (v4f){o[4], o[5], o[6], o[7]};

        // Flush pass p immediately: wave-local slots [128p, 128p+128) =
        // flush iterations j in {2p, 2p+1}. Dense 1KB per store instruction.
#pragma unroll
        for (int jj = 0; jj < 2; ++jj) {
            const int j = 2 * p + jj;
            const int s = j * 64 + l;
            v4f val = (s & 1) ? outB[w][s >> 1] : outA[w][s >> 1];
            const int gslot = (j < 2) ? (128 * w + j * 64 + l)
                                      : (512 + 128 * w + (j - 2) * 64 + l);
            __builtin_nontemporal_store(val, ov + gslot);
        }
    }
}

extern "C" void kernel_launch(void* const* d_in, const int* in_sizes, int n_in,
                              void* d_out, int out_size, void* d_ws, size_t ws_size,
                              hipStream_t stream) {
    const float* x = (const float*)d_in[0];
    float* out = (float*)d_out;

    const int tokens = in_sizes[0] / 8;        // 1,048,576
    const int grid = tokens / (BLOCK * TPT);   // 2048

    e8q_kernel<<<grid, BLOCK, 0, stream>>>(x, out);
}